// Round 3
// baseline (1970.219 us; speedup 1.0000x reference)
//
#include <hip/hip_runtime.h>

// WL graph kernel: G=64 graphs, N=4096 nodes, D=16 neighbors, 4 iterations.
// K[g][g'] = <F_g, F_g'> where F = summed label histograms over 5 label sets
// (initial arange + 4 refinements), then cosine-normalized.
//
// Invariance: K depends only on signature equality classes (shared dict across
// graphs, disjoint id ranges per iteration), so we replace lexsort-rank ids with
// a hash-table dedup + atomic-counter dense ids, and use a commutative multiset
// hash (no neighbor sorting needed).

#define GG 64
#define NN 4096
#define DD 16
#define TT 4

static constexpr int GN = GG * NN;           // 262144 nodes total
static constexpr int HSIZE = 1 << 19;        // hash slots (load factor <= 0.5)
static constexpr unsigned HMASK = HSIZE - 1;
static constexpr int CMAX = GN;              // max distinct classes per iteration

__device__ __forceinline__ unsigned long long mix64(unsigned long long x) {
    x += 0x9E3779B97F4A7C15ull;
    x = (x ^ (x >> 30)) * 0xBF58476D1CE4E5B9ull;
    x = (x ^ (x >> 27)) * 0x94D049BB133111EBull;
    return x ^ (x >> 31);
}

// labels[g][i] = i; cnt[class=i][g] = w[g][i]  (iteration-0 histogram)
__global__ void k_init(int* __restrict__ labels, const float* __restrict__ w,
                       float* __restrict__ cnt) {
    int idx = blockIdx.x * blockDim.x + threadIdx.x;   // 0..GN
    int g = idx >> 12;
    int i = idx & (NN - 1);
    labels[idx] = i;
    cnt[i * GG + g] = w[idx];                          // cnt pre-zeroed; unique (i,g)
}

// Phase 1: build signature hash, claim hash slot, record slot + keep flag.
__global__ void k_hash(const int* __restrict__ labels, const int* __restrict__ nbr,
                       unsigned long long* __restrict__ keys, int* __restrict__ ids,
                       int* __restrict__ counter, int* __restrict__ slotOf) {
    int idx = blockIdx.x * blockDim.x + threadIdx.x;
    int g = idx >> 12;
    const int* lab = labels + (g << 12);
    int own = lab[idx & (NN - 1)];

    const int4* nb4 = reinterpret_cast<const int4*>(nbr + (size_t)idx * DD);
    unsigned long long acc = 0;
    bool keep = true;
#pragma unroll
    for (int q = 0; q < 4; ++q) {
        int4 v = nb4[q];
        int l0 = lab[v.x], l1 = lab[v.y], l2 = lab[v.z], l3 = lab[v.w];
        keep = keep & (l0 == own) & (l1 == own) & (l2 == own) & (l3 == own);
        // commutative multiset hash: sum of per-element mixes
        acc += mix64((unsigned long long)(unsigned)l0)
             + mix64((unsigned long long)(unsigned)l1)
             + mix64((unsigned long long)(unsigned)l2)
             + mix64((unsigned long long)(unsigned)l3);
    }
    unsigned long long h =
        mix64(acc ^ mix64(((unsigned long long)(unsigned)own) + 0x0ABCDEF123456789ull));
    if (h == 0ull) h = 0x9E3779B97F4A7C15ull;   // 0 is the EMPTY sentinel

    unsigned slot = (unsigned)h & HMASK;
    while (true) {
        unsigned long long old = atomicCAS(&keys[slot], 0ull, h);
        if (old == 0ull) {                       // we claimed this slot
            ids[slot] = atomicAdd(counter, 1);   // read only in phase 2 (next kernel)
            break;
        }
        if (old == h) break;                     // existing class
        slot = (slot + 1) & HMASK;
    }
    slotOf[idx] = (int)slot | (keep ? (int)0x80000000 : 0);
}

// Phase 2: resolve dense id, count per (class, graph), write next labels.
__global__ void k_resolve(const int* __restrict__ labels, const int* __restrict__ slotOf,
                          const int* __restrict__ ids, const float* __restrict__ w,
                          float* __restrict__ cnt, int* __restrict__ labels_next,
                          int offset) {
    int idx = blockIdx.x * blockDim.x + threadIdx.x;
    int g = idx >> 12;
    int s = slotOf[idx];
    int slot = s & 0x7FFFFFFF;
    int id = ids[slot];
    atomicAdd(&cnt[(size_t)id * GG + g], w[idx]);
    labels_next[idx] = (s < 0) ? labels[idx] : (offset + id);
}

// Fold: K += Cnt^T * Cnt over this block's chunk of 256 classes; re-zero cnt.
// grid = C/256 blocks, 256 threads; each thread owns a 4x4 tile of the 64x64 K.
__global__ void k_fold(float* __restrict__ cnt, double* __restrict__ K) {
    int e0 = blockIdx.x * 256;
    __shared__ float v[32 * 64];
    float acc[16];
#pragma unroll
    for (int k = 0; k < 16; ++k) acc[k] = 0.f;
    int r0 = (threadIdx.x >> 4) << 2;
    int c0 = (threadIdx.x & 15) << 2;

    for (int s0 = 0; s0 < 256; s0 += 32) {
        size_t base = (size_t)(e0 + s0) * 64;
#pragma unroll
        for (int k = 0; k < 8; ++k) {
            int t = threadIdx.x + k * 256;
            v[t] = cnt[base + t];
        }
        __syncthreads();
#pragma unroll
        for (int e = 0; e < 32; ++e) {
            const float4 a = *reinterpret_cast<const float4*>(&v[e * 64 + r0]);
            const float4 b = *reinterpret_cast<const float4*>(&v[e * 64 + c0]);
            acc[0]  += a.x * b.x; acc[1]  += a.x * b.y; acc[2]  += a.x * b.z; acc[3]  += a.x * b.w;
            acc[4]  += a.y * b.x; acc[5]  += a.y * b.y; acc[6]  += a.y * b.z; acc[7]  += a.y * b.w;
            acc[8]  += a.z * b.x; acc[9]  += a.z * b.y; acc[10] += a.z * b.z; acc[11] += a.z * b.w;
            acc[12] += a.w * b.x; acc[13] += a.w * b.y; acc[14] += a.w * b.z; acc[15] += a.w * b.w;
        }
        __syncthreads();
    }
    // re-zero this block's chunk (next iteration reuses cnt)
    size_t zbase = (size_t)e0 * 64;
    for (int k = threadIdx.x; k < 256 * 64; k += 256) cnt[zbase + k] = 0.f;
#pragma unroll
    for (int i = 0; i < 4; ++i)
#pragma unroll
        for (int j = 0; j < 4; ++j)
            atomicAdd(&K[(r0 + i) * 64 + (c0 + j)], (double)acc[i * 4 + j]);
}

__global__ void k_norm(const double* __restrict__ K, float* __restrict__ out) {
    int idx = blockIdx.x * blockDim.x + threadIdx.x;   // 4096
    int r = idx >> 6, c = idx & 63;
    double d = sqrt(K[r * 64 + r] * K[c * 64 + c]);
    out[idx] = (float)(K[idx] / d);
}

extern "C" void kernel_launch(void* const* d_in, const int* in_sizes, int n_in,
                              void* d_out, int out_size, void* d_ws, size_t ws_size,
                              hipStream_t stream) {
    const int* nbr = (const int*)d_in[0];       // [G, N, D] int32
    const float* w = (const float*)d_in[1];     // [G, N] float32
    float* out = (float*)d_out;                 // [G, G] float32

    char* ws = (char*)d_ws;
    size_t off = 0;
    auto alloc = [&](size_t bytes) -> void* {
        void* p = ws + off;
        off += (bytes + 255) & ~(size_t)255;
        return p;
    };
    int* labelsA = (int*)alloc((size_t)GN * 4);                     // 1 MB
    int* labelsB = (int*)alloc((size_t)GN * 4);                     // 1 MB
    int* slotOf  = (int*)alloc((size_t)GN * 4);                     // 1 MB
    unsigned long long* keys = (unsigned long long*)alloc((size_t)HSIZE * 8); // 4 MB
    int* ids     = (int*)alloc((size_t)HSIZE * 4);                  // 2 MB
    int* counters = (int*)alloc(256);                               // 64 ints
    double* Kacc = (double*)alloc(64 * 64 * 8);                     // 32 KB
    float* cnt   = (float*)alloc((size_t)CMAX * GG * 4);            // 64 MB
    // counters, Kacc, cnt are contiguous (all sizes multiple of 256): one memset
    hipMemsetAsync(counters, 0, 256 + 64 * 64 * 8 + (size_t)CMAX * GG * 4, stream);

    const int BLK = 256;
    const int GRID_NODES = GN / BLK;   // 1024

    // iteration 0: labels = arange, histogram = node_weights
    k_init<<<GRID_NODES, BLK, 0, stream>>>(labelsA, w, cnt);
    k_fold<<<NN / 256, BLK, 0, stream>>>(cnt, Kacc);   // 16 blocks (classes 0..4095)

    int* cur = labelsA;
    int* nxt = labelsB;
    for (int t = 0; t < TT; ++t) {
        hipMemsetAsync(keys, 0, (size_t)HSIZE * 8, stream);
        k_hash<<<GRID_NODES, BLK, 0, stream>>>(cur, nbr, keys, ids, &counters[t], slotOf);
        k_resolve<<<GRID_NODES, BLK, 0, stream>>>(cur, slotOf, ids, w, cnt, nxt,
                                                  NN + t * GN);
        k_fold<<<CMAX / 256, BLK, 0, stream>>>(cnt, Kacc);  // 1024 blocks
        int* tmp = cur; cur = nxt; nxt = tmp;
    }

    k_norm<<<(GG * GG) / BLK, BLK, 0, stream>>>(Kacc, out);
}

// Round 4
// 863.302 us; speedup vs baseline: 2.2822x; 2.2822x over previous
//
#include <hip/hip_runtime.h>

// WL graph kernel: G=64 graphs, N=4096 nodes, D=16 neighbors, 4 iterations.
// K = cosine-normalized Gram of summed per-iteration label histograms.
// Hash-dedup with commutative multiset hash replaces lexsort ranking (any
// injective class->id map with disjoint per-iteration ranges gives the same K).
//
// R4: wave-aggregated counter atomics (was 262144 same-address adds -> 255us
// serialization), LDS-staged label gathers, re-chunked fold (4x fewer Kacc atomics).

#define GG 64
#define NN 4096
#define DD 16
#define TT 4

static constexpr int GN = GG * NN;           // 262144 nodes total
static constexpr int HSIZE = 1 << 19;        // hash slots (load factor <= 0.5)
static constexpr unsigned HMASK = HSIZE - 1;
static constexpr int CMAX = GN;              // max distinct classes per iteration
static constexpr int FOLD_CHUNK = 1024;      // classes per fold block

__device__ __forceinline__ unsigned long long mix64(unsigned long long x) {
    x += 0x9E3779B97F4A7C15ull;
    x = (x ^ (x >> 30)) * 0xBF58476D1CE4E5B9ull;
    x = (x ^ (x >> 27)) * 0x94D049BB133111EBull;
    return x ^ (x >> 31);
}

// labels[g][i] = i; cnt[class=i][g] = w[g][i]  (iteration-0 histogram)
__global__ void k_init(int* __restrict__ labels, const float* __restrict__ w,
                       float* __restrict__ cnt) {
    int idx = blockIdx.x * blockDim.x + threadIdx.x;   // 0..GN
    int g = idx >> 12;
    int i = idx & (NN - 1);
    labels[idx] = i;
    cnt[i * GG + g] = w[idx];                          // cnt pre-zeroed; unique (i,g)
}

// Phase 1: signature hash, CAS-claim slot, wave-aggregated dense-id alloc.
// 1024 threads/block, one graph per 4 blocks; labels staged in LDS (16 KB).
__global__ __launch_bounds__(1024) void
k_hash(const int* __restrict__ labels, const int* __restrict__ nbr,
       unsigned long long* __restrict__ keys, int* __restrict__ ids,
       int* __restrict__ counter, int* __restrict__ slotOf) {
    __shared__ int slab[NN];
    int tid = threadIdx.x;
    int g = blockIdx.x >> 2;
    int node = ((blockIdx.x & 3) << 10) | tid;
    const int* lab = labels + (g << 12);
    reinterpret_cast<int4*>(slab)[tid] = reinterpret_cast<const int4*>(lab)[tid];
    __syncthreads();

    int idx = (g << 12) | node;
    int own = slab[node];

    const int4* nb4 = reinterpret_cast<const int4*>(nbr + (size_t)idx * DD);
    unsigned long long acc = 0;
    bool keep = true;
#pragma unroll
    for (int q = 0; q < 4; ++q) {
        int4 v = nb4[q];
        int l0 = slab[v.x], l1 = slab[v.y], l2 = slab[v.z], l3 = slab[v.w];
        keep = keep & (l0 == own) & (l1 == own) & (l2 == own) & (l3 == own);
        acc += mix64((unsigned long long)(unsigned)l0)
             + mix64((unsigned long long)(unsigned)l1)
             + mix64((unsigned long long)(unsigned)l2)
             + mix64((unsigned long long)(unsigned)l3);
    }
    unsigned long long h =
        mix64(acc ^ mix64(((unsigned long long)(unsigned)own) + 0x0ABCDEF123456789ull));
    if (h == 0ull) h = 0x9E3779B97F4A7C15ull;   // 0 is the EMPTY sentinel

    unsigned slot = (unsigned)h & HMASK;
    bool claimed = false;
    while (true) {
        unsigned long long old = atomicCAS(&keys[slot], 0ull, h);
        if (old == 0ull) { claimed = true; break; }
        if (old == h) break;
        slot = (slot + 1) & HMASK;
    }
    // reconverged: one counter atomic per wave, distribute base + prefix rank
    unsigned long long b = __ballot(claimed);
    if (b) {
        int lane = tid & 63;
        int leader = (int)__ffsll(b) - 1;
        int base = 0;
        if (lane == leader) base = atomicAdd(counter, (int)__popcll(b));
        base = __shfl(base, leader, 64);
        if (claimed)
            ids[slot] = base + (int)__popcll(b & ((1ull << lane) - 1ull));
    }
    slotOf[idx] = (int)slot | (keep ? (int)0x80000000 : 0);
}

// Phase 2: resolve dense id, count per (class, graph), write next labels.
__global__ void k_resolve(const int* __restrict__ labels, const int* __restrict__ slotOf,
                          const int* __restrict__ ids, const float* __restrict__ w,
                          float* __restrict__ cnt, int* __restrict__ labels_next,
                          int offset) {
    int idx = blockIdx.x * blockDim.x + threadIdx.x;
    int g = idx >> 12;
    int s = slotOf[idx];
    int slot = s & 0x7FFFFFFF;
    int id = ids[slot];
    atomicAdd(&cnt[(size_t)id * GG + g], w[idx]);
    labels_next[idx] = (s < 0) ? labels[idx] : (offset + id);
}

// Fold: K += Cnt^T * Cnt over this block's FOLD_CHUNK classes; re-zero cnt.
// 256 threads; each thread owns a 4x4 tile of the 64x64 K.
__global__ void k_fold(float* __restrict__ cnt, double* __restrict__ K) {
    int e0 = blockIdx.x * FOLD_CHUNK;
    __shared__ float v[32 * 64];
    float acc[16];
#pragma unroll
    for (int k = 0; k < 16; ++k) acc[k] = 0.f;
    int r0 = (threadIdx.x >> 4) << 2;
    int c0 = (threadIdx.x & 15) << 2;

    for (int s0 = 0; s0 < FOLD_CHUNK; s0 += 32) {
        const float4* src = reinterpret_cast<const float4*>(cnt + (size_t)(e0 + s0) * 64);
        float4* dv = reinterpret_cast<float4*>(v);
        dv[threadIdx.x] = src[threadIdx.x];
        dv[threadIdx.x + 256] = src[threadIdx.x + 256];
        __syncthreads();
#pragma unroll
        for (int e = 0; e < 32; ++e) {
            const float4 a = *reinterpret_cast<const float4*>(&v[e * 64 + r0]);
            const float4 b = *reinterpret_cast<const float4*>(&v[e * 64 + c0]);
            acc[0]  += a.x * b.x; acc[1]  += a.x * b.y; acc[2]  += a.x * b.z; acc[3]  += a.x * b.w;
            acc[4]  += a.y * b.x; acc[5]  += a.y * b.y; acc[6]  += a.y * b.z; acc[7]  += a.y * b.w;
            acc[8]  += a.z * b.x; acc[9]  += a.z * b.y; acc[10] += a.z * b.z; acc[11] += a.z * b.w;
            acc[12] += a.w * b.x; acc[13] += a.w * b.y; acc[14] += a.w * b.z; acc[15] += a.w * b.w;
        }
        __syncthreads();
    }
    // re-zero this block's chunk (next iteration reuses cnt)
    float4* z = reinterpret_cast<float4*>(cnt + (size_t)e0 * 64);
    for (int k = threadIdx.x; k < FOLD_CHUNK * 64 / 4; k += 256)
        z[k] = float4{0.f, 0.f, 0.f, 0.f};
#pragma unroll
    for (int i = 0; i < 4; ++i)
#pragma unroll
        for (int j = 0; j < 4; ++j)
            atomicAdd(&K[(r0 + i) * 64 + (c0 + j)], (double)acc[i * 4 + j]);
}

__global__ void k_norm(const double* __restrict__ K, float* __restrict__ out) {
    int idx = blockIdx.x * blockDim.x + threadIdx.x;   // 4096
    int r = idx >> 6, c = idx & 63;
    double d = sqrt(K[r * 64 + r] * K[c * 64 + c]);
    out[idx] = (float)(K[idx] / d);
}

extern "C" void kernel_launch(void* const* d_in, const int* in_sizes, int n_in,
                              void* d_out, int out_size, void* d_ws, size_t ws_size,
                              hipStream_t stream) {
    const int* nbr = (const int*)d_in[0];       // [G, N, D] int32
    const float* w = (const float*)d_in[1];     // [G, N] float32
    float* out = (float*)d_out;                 // [G, G] float32

    char* ws = (char*)d_ws;
    size_t off = 0;
    auto alloc = [&](size_t bytes) -> void* {
        void* p = ws + off;
        off += (bytes + 255) & ~(size_t)255;
        return p;
    };
    int* labelsA = (int*)alloc((size_t)GN * 4);                     // 1 MB
    int* labelsB = (int*)alloc((size_t)GN * 4);                     // 1 MB
    int* slotOf  = (int*)alloc((size_t)GN * 4);                     // 1 MB
    unsigned long long* keys = (unsigned long long*)alloc((size_t)HSIZE * 8); // 4 MB
    int* ids     = (int*)alloc((size_t)HSIZE * 4);                  // 2 MB
    int* counters = (int*)alloc(256);                               // 64 ints
    double* Kacc = (double*)alloc(64 * 64 * 8);                     // 32 KB
    float* cnt   = (float*)alloc((size_t)CMAX * GG * 4);            // 64 MB
    // counters, Kacc, cnt are contiguous (sizes multiple of 256): one memset
    hipMemsetAsync(counters, 0, 256 + 64 * 64 * 8 + (size_t)CMAX * GG * 4, stream);

    const int BLK = 256;
    const int GRID_NODES = GN / BLK;   // 1024

    // iteration 0: labels = arange, histogram = node_weights (classes 0..4095)
    k_init<<<GRID_NODES, BLK, 0, stream>>>(labelsA, w, cnt);
    k_fold<<<NN / FOLD_CHUNK, BLK, 0, stream>>>(cnt, Kacc);   // 4 blocks

    int* cur = labelsA;
    int* nxt = labelsB;
    for (int t = 0; t < TT; ++t) {
        hipMemsetAsync(keys, 0, (size_t)HSIZE * 8, stream);
        k_hash<<<GN / 1024, 1024, 0, stream>>>(cur, nbr, keys, ids, &counters[t], slotOf);
        k_resolve<<<GRID_NODES, BLK, 0, stream>>>(cur, slotOf, ids, w, cnt, nxt,
                                                  NN + t * GN);
        k_fold<<<CMAX / FOLD_CHUNK, BLK, 0, stream>>>(cnt, Kacc);  // 256 blocks
        int* tmp = cur; cur = nxt; nxt = tmp;
    }

    k_norm<<<(GG * GG) / BLK, BLK, 0, stream>>>(Kacc, out);
}

// Round 5
// 256.603 us; speedup vs baseline: 7.6781x; 3.3643x over previous
//
#include <hip/hip_runtime.h>

// WL graph kernel: G=64 graphs, N=4096 nodes, D=16 neighbors, 4 iterations.
// K = cosine-normalized Gram of summed per-iteration label histograms.
//
// R5: no dense histogram. K = sum_t K_t (disjoint label ranges), and
// K_t[g][g'] = sum over ordered same-class node pairs (u,v) of w_u*w_v.
// Classes come from a hash table (commutative multiset hash of neighbor
// labels + own label); per-slot linked lists give the pair enumeration.
// Iteration-0 (labels=arange) is K0 = W*W^T, folded from transposed weights.
// Labels ARE the hash slots ((t+1)<<19 + slot): injective per iteration,
// disjoint across iterations -> no dense-id counter at all.

#define GG 64
#define NN 4096
#define DD 16
#define TT 4

static constexpr int GN = GG * NN;           // 262144 nodes total
static constexpr int HSIZE = 1 << 19;        // hash slots (load factor <= 0.5)
static constexpr unsigned HMASK = HSIZE - 1;

__device__ __forceinline__ unsigned long long mix64(unsigned long long x) {
    x += 0x9E3779B97F4A7C15ull;
    x = (x ^ (x >> 30)) * 0xBF58476D1CE4E5B9ull;
    x = (x ^ (x >> 27)) * 0x94D049BB133111EBull;
    return x ^ (x >> 31);
}

// labels[g][i] = i;  wT[i][g] = w[g][i]  (for the iteration-0 W*W^T fold)
__global__ void k_init(int* __restrict__ labels, const float* __restrict__ w,
                       float* __restrict__ wT) {
    int idx = blockIdx.x * blockDim.x + threadIdx.x;   // 0..GN
    labels[idx] = idx & (NN - 1);
    int i = idx >> 6, g = idx & 63;
    wT[idx] = w[(g << 12) | i];
}

// Phase 1: signature hash, CAS-claim slot, build per-slot linked lists,
// write next labels. 1024 threads/block; labels staged in LDS (16 KB).
__global__ __launch_bounds__(1024) void
k_hash(const int* __restrict__ labels, const int* __restrict__ nbr,
       unsigned long long* __restrict__ keys, int* __restrict__ head,
       int* __restrict__ next, int* __restrict__ slotOf,
       int* __restrict__ labels_next, int base) {
    __shared__ int slab[NN];
    int tid = threadIdx.x;
    int g = blockIdx.x >> 2;
    int node = ((blockIdx.x & 3) << 10) | tid;
    const int* lab = labels + (g << 12);
    reinterpret_cast<int4*>(slab)[tid] = reinterpret_cast<const int4*>(lab)[tid];
    __syncthreads();

    int idx = (g << 12) | node;
    int own = slab[node];

    const int4* nb4 = reinterpret_cast<const int4*>(nbr + (size_t)idx * DD);
    unsigned long long acc = 0;
    bool keep = true;
#pragma unroll
    for (int q = 0; q < 4; ++q) {
        int4 v = nb4[q];
        int l0 = slab[v.x], l1 = slab[v.y], l2 = slab[v.z], l3 = slab[v.w];
        keep = keep & (l0 == own) & (l1 == own) & (l2 == own) & (l3 == own);
        acc += mix64((unsigned long long)(unsigned)l0)
             + mix64((unsigned long long)(unsigned)l1)
             + mix64((unsigned long long)(unsigned)l2)
             + mix64((unsigned long long)(unsigned)l3);
    }
    unsigned long long h =
        mix64(acc ^ mix64(((unsigned long long)(unsigned)own) + 0x0ABCDEF123456789ull));
    if (h == 0ull) h = 0x9E3779B97F4A7C15ull;   // 0 is the EMPTY sentinel

    unsigned slot = (unsigned)h & HMASK;
    while (true) {
        unsigned long long old = atomicCAS(&keys[slot], 0ull, h);
        if (old == 0ull || old == h) break;
        slot = (slot + 1) & HMASK;
    }
    slotOf[idx] = (int)slot;
    labels_next[idx] = keep ? own : (base + (int)slot);
    next[idx] = atomicExch(&head[slot], idx);   // prepend to class list
}

// Phase 2: enumerate same-class ordered pairs. Same-graph contributions are
// block-reduced (one fp64 atomic per block); cross-graph pairs (rare) atomic.
__global__ void k_pairs(const int* __restrict__ slotOf, const int* __restrict__ head,
                        const int* __restrict__ next, const float* __restrict__ w,
                        double* __restrict__ K) {
    int idx = blockIdx.x * blockDim.x + threadIdx.x;
    int g = idx >> 12;                          // whole block is one graph
    int slot = slotOf[idx];
    float wu = w[idx];
    double diag = 0.0;
    for (int v = head[slot]; v >= 0; v = next[v]) {
        int gv = v >> 12;
        float wv = w[v];
        if (gv == g) diag += (double)wu * wv;   // includes the self pair
        else atomicAdd(&K[(g << 6) | gv], (double)wu * wv);
    }
    // wave reduce, then block reduce the same-graph sum
#pragma unroll
    for (int o = 32; o > 0; o >>= 1) diag += __shfl_down(diag, o, 64);
    __shared__ double part[4];
    int lane = threadIdx.x & 63, wv_ = threadIdx.x >> 6;
    if (lane == 0) part[wv_] = diag;
    __syncthreads();
    if (threadIdx.x == 0)
        atomicAdd(&K[(g << 6) | g], part[0] + part[1] + part[2] + part[3]);
}

// Fold K += src^T * src over [rows=chunk*gridDim][64]; thread owns 4x4 tile.
__global__ void k_fold(const float* __restrict__ src, double* __restrict__ K,
                       int chunk) {
    int e0 = blockIdx.x * chunk;
    __shared__ float v[32 * 64];
    float acc[16];
#pragma unroll
    for (int k = 0; k < 16; ++k) acc[k] = 0.f;
    int r0 = (threadIdx.x >> 4) << 2;
    int c0 = (threadIdx.x & 15) << 2;

    for (int s0 = 0; s0 < chunk; s0 += 32) {
        const float4* s4 = reinterpret_cast<const float4*>(src + (size_t)(e0 + s0) * 64);
        float4* dv = reinterpret_cast<float4*>(v);
        dv[threadIdx.x] = s4[threadIdx.x];
        dv[threadIdx.x + 256] = s4[threadIdx.x + 256];
        __syncthreads();
#pragma unroll
        for (int e = 0; e < 32; ++e) {
            const float4 a = *reinterpret_cast<const float4*>(&v[e * 64 + r0]);
            const float4 b = *reinterpret_cast<const float4*>(&v[e * 64 + c0]);
            acc[0]  += a.x * b.x; acc[1]  += a.x * b.y; acc[2]  += a.x * b.z; acc[3]  += a.x * b.w;
            acc[4]  += a.y * b.x; acc[5]  += a.y * b.y; acc[6]  += a.y * b.z; acc[7]  += a.y * b.w;
            acc[8]  += a.z * b.x; acc[9]  += a.z * b.y; acc[10] += a.z * b.z; acc[11] += a.z * b.w;
            acc[12] += a.w * b.x; acc[13] += a.w * b.y; acc[14] += a.w * b.z; acc[15] += a.w * b.w;
        }
        __syncthreads();
    }
#pragma unroll
    for (int i = 0; i < 4; ++i)
#pragma unroll
        for (int j = 0; j < 4; ++j)
            atomicAdd(&K[(r0 + i) * 64 + (c0 + j)], (double)acc[i * 4 + j]);
}

__global__ void k_norm(const double* __restrict__ K, float* __restrict__ out) {
    int idx = blockIdx.x * blockDim.x + threadIdx.x;   // 4096
    int r = idx >> 6, c = idx & 63;
    double d = sqrt(K[r * 64 + r] * K[c * 64 + c]);
    out[idx] = (float)(K[idx] / d);
}

extern "C" void kernel_launch(void* const* d_in, const int* in_sizes, int n_in,
                              void* d_out, int out_size, void* d_ws, size_t ws_size,
                              hipStream_t stream) {
    const int* nbr = (const int*)d_in[0];       // [G, N, D] int32
    const float* w = (const float*)d_in[1];     // [G, N] float32
    float* out = (float*)d_out;                 // [G, G] float32

    char* ws = (char*)d_ws;
    size_t off = 0;
    auto alloc = [&](size_t bytes) -> void* {
        void* p = ws + off;
        off += (bytes + 255) & ~(size_t)255;
        return p;
    };
    int* labelsA = (int*)alloc((size_t)GN * 4);                     // 1 MB
    int* labelsB = (int*)alloc((size_t)GN * 4);                     // 1 MB
    int* slotOf  = (int*)alloc((size_t)GN * 4);                     // 1 MB
    int* next    = (int*)alloc((size_t)GN * 4);                     // 1 MB
    float* wT    = (float*)alloc((size_t)GN * 4);                   // 1 MB
    double* Kacc = (double*)alloc(64 * 64 * 8);                     // 32 KB
    unsigned long long* keys = (unsigned long long*)alloc((size_t)TT * HSIZE * 8); // 16 MB
    int* head    = (int*)alloc((size_t)TT * HSIZE * 4);             // 8 MB
    // Kacc and keys are contiguous: one zero-memset; head needs 0xFF (-1).
    hipMemsetAsync(Kacc, 0, 64 * 64 * 8 + (size_t)TT * HSIZE * 8, stream);
    hipMemsetAsync(head, 0xFF, (size_t)TT * HSIZE * 4, stream);

    const int BLK = 256;
    const int GRID_NODES = GN / BLK;   // 1024

    // iteration 0: labels = arange shared across graphs -> K0 = W W^T
    k_init<<<GRID_NODES, BLK, 0, stream>>>(labelsA, w, wT);
    k_fold<<<32, BLK, 0, stream>>>(wT, Kacc, NN / 32);   // 32 blocks x 128 rows

    int* cur = labelsA;
    int* nxt = labelsB;
    for (int t = 0; t < TT; ++t) {
        k_hash<<<GN / 1024, 1024, 0, stream>>>(cur, nbr, keys + (size_t)t * HSIZE,
                                               head + (size_t)t * HSIZE, next,
                                               slotOf, nxt, (t + 1) << 19);
        k_pairs<<<GRID_NODES, BLK, 0, stream>>>(slotOf, head + (size_t)t * HSIZE,
                                                next, w, Kacc);
        int* tmp = cur; cur = nxt; nxt = tmp;
    }

    k_norm<<<(GG * GG) / BLK, BLK, 0, stream>>>(Kacc, out);
}

// Round 7
// 173.399 us; speedup vs baseline: 11.3623x; 1.4798x over previous
//
#include <hip/hip_runtime.h>

// WL graph kernel: G=64 graphs, N=4096 nodes, D=16 neighbors, 4 iterations.
// K = cosine-normalized Gram of summed per-iteration label histograms.
//
// R6: K = W*W^T (iter 0)  +  4*diag(s_g), s_g = sum_u w_u^2  (singleton classes,
// iteration-independent)  +  corrections for multi-member classes (rare).
// Dedup via ONE 64-bit CAS per node into table[pos] = (tag32<<32)|(idx+1):
// the CAS both claims the class slot and publishes the representative node.
// Joiners (old tag match) inline their pair with the rep and go to an overflow
// list for joiner-joiner pairs. Labels ARE the slots (base_t + pos), injective
// per class (53-bit hash check), disjoint ranges per iteration.

#define GG 64
#define NN 4096
#define DD 16
#define TT 4

static constexpr int GN = GG * NN;             // 262144 nodes
static constexpr int PBITS = 21;               // 2^21 slots, 12.5% load
static constexpr unsigned PMASK = (1u << PBITS) - 1;
static constexpr size_t TBYTES = (size_t)8 << PBITS;   // 16 MB
static constexpr int OVF_MAX = GN;

__device__ __forceinline__ unsigned long long mix64(unsigned long long x) {
    x += 0x9E3779B97F4A7C15ull;
    x = (x ^ (x >> 30)) * 0xBF58476D1CE4E5B9ull;
    x = (x ^ (x >> 27)) * 0x94D049BB133111EBull;
    return x ^ (x >> 31);
}

// labels[g][i] = i;  wT[i][g] = w[g][i]  (for the iteration-0 W*W^T fold)
__global__ void k_init(int* __restrict__ labels, const float* __restrict__ w,
                       float* __restrict__ wT) {
    int idx = blockIdx.x * blockDim.x + threadIdx.x;   // 0..GN
    labels[idx] = idx & (NN - 1);
    int i = idx >> 6, g = idx & 63;
    wT[idx] = w[(g << 12) | i];
}

// Signature hash + single-CAS dedup + label write. 512 thr, 8 blocks/graph.
__global__ __launch_bounds__(512) void
k_hash(const int* __restrict__ labels, const int* __restrict__ nbr,
       unsigned long long* __restrict__ table, const float* __restrict__ w,
       double* __restrict__ K, unsigned long long* __restrict__ ovf,
       int* __restrict__ novf, int* __restrict__ labels_next, int base) {
    __shared__ int slab[NN];
    int tid = threadIdx.x;
    int g = blockIdx.x >> 3;
    int node = ((blockIdx.x & 7) << 9) | tid;
    {
        const int4* l4 = reinterpret_cast<const int4*>(labels + (g << 12));
        int4* s4 = reinterpret_cast<int4*>(slab);
        s4[tid] = l4[tid];
        s4[tid + 512] = l4[tid + 512];
    }
    __syncthreads();

    int idx = (g << 12) | node;
    int own = slab[node];

    const int4* nb4 = reinterpret_cast<const int4*>(nbr + (size_t)idx * DD);
    unsigned long long acc = 0;
    bool keep = true;
#pragma unroll
    for (int q = 0; q < 4; ++q) {
        int4 v = nb4[q];
        int l0 = slab[v.x], l1 = slab[v.y], l2 = slab[v.z], l3 = slab[v.w];
        keep = keep & (l0 == own) & (l1 == own) & (l2 == own) & (l3 == own);
        acc += mix64((unsigned long long)(unsigned)l0)
             + mix64((unsigned long long)(unsigned)l1)
             + mix64((unsigned long long)(unsigned)l2)
             + mix64((unsigned long long)(unsigned)l3);
    }
    unsigned long long h =
        mix64(acc ^ mix64(((unsigned long long)(unsigned)own) + 0x0ABCDEF123456789ull));

    unsigned pos = (unsigned)(h >> 40) & PMASK;      // bits 40..60
    unsigned tag = (unsigned)h;                      // bits 0..31 (independent)
    unsigned long long val = ((unsigned long long)tag << 32) | (unsigned)(idx + 1);
    int rep = -1;
    while (true) {
        unsigned long long old = atomicCAS(&table[pos], 0ull, val);
        if (old == 0ull) break;                              // claimed: we are rep
        if ((unsigned)(old >> 32) == tag) {                  // same class
            rep = (int)(old & 0xFFFFFFFFull) - 1;
            break;
        }
        pos = (pos + 1) & PMASK;                             // different class
    }
    labels_next[idx] = keep ? own : (base + (int)pos);

    bool join = rep >= 0;                    // ~never on this input; exact path
    if (join) {
        double duv = (double)w[idx] * (double)w[rep];
        int gr = rep >> 12;
        atomicAdd(&K[(g << 6) | gr], duv);   // ordered pair (u, rep)
        atomicAdd(&K[(gr << 6) | g], duv);   // ordered pair (rep, u)
    }
    unsigned long long b = __ballot(join);
    if (b) {
        int lane = tid & 63;
        int leader = (int)__ffsll(b) - 1;
        int bp = 0;
        if (lane == leader) bp = atomicAdd(novf, (int)__popcll(b));
        bp = __shfl(bp, leader, 64);
        if (join) {
            int p = bp + (int)__popcll(b & ((1ull << lane) - 1ull));
            if (p < OVF_MAX)
                ovf[p] = ((unsigned long long)pos << 32) | (unsigned)idx;
        }
    }
}

// Joiner-joiner ordered pairs (same slot => same class). Usually novf == 0.
__global__ void k_resolve(const unsigned long long* __restrict__ ovf,
                          const int* __restrict__ novf,
                          const float* __restrict__ w, double* __restrict__ K) {
    int n = *novf;
    if (n > OVF_MAX) n = OVF_MAX;
    int i = blockIdx.x * blockDim.x + threadIdx.x;
    if (i >= n) return;
    unsigned long long e = ovf[i];
    unsigned pos = (unsigned)(e >> 32);
    int u = (int)(e & 0xFFFFFFFFull);
    int gu = u >> 12;
    double wu = w[u];
    for (int j = 0; j < n; ++j) {
        if (j == i) continue;
        unsigned long long f = ovf[j];
        if ((unsigned)(f >> 32) != pos) continue;
        int v = (int)(f & 0xFFFFFFFFull);
        atomicAdd(&K[(gu << 6) | (v >> 12)], wu * (double)w[v]);
    }
}

// s_g = sum_u w[g][u]^2  (one block per graph)
__global__ void k_diag(const float* __restrict__ w, double* __restrict__ sdiag) {
    int g = blockIdx.x;
    const float4* w4 = reinterpret_cast<const float4*>(w + (g << 12));
    double s = 0.0;
    for (int k = threadIdx.x; k < NN / 4; k += 256) {
        float4 v = w4[k];
        s += (double)v.x * v.x + (double)v.y * v.y
           + (double)v.z * v.z + (double)v.w * v.w;
    }
#pragma unroll
    for (int o = 32; o > 0; o >>= 1) s += __shfl_down(s, o, 64);
    __shared__ double part[4];
    if ((threadIdx.x & 63) == 0) part[threadIdx.x >> 6] = s;
    __syncthreads();
    if (threadIdx.x == 0) sdiag[g] = part[0] + part[1] + part[2] + part[3];
}

// Fold K += src^T * src over [rows][64]; thread owns 4x4 tile of 64x64 K.
__global__ void k_fold(const float* __restrict__ src, double* __restrict__ K,
                       int chunk) {
    int e0 = blockIdx.x * chunk;
    __shared__ float v[32 * 64];
    float acc[16];
#pragma unroll
    for (int k = 0; k < 16; ++k) acc[k] = 0.f;
    int r0 = (threadIdx.x >> 4) << 2;
    int c0 = (threadIdx.x & 15) << 2;

    for (int s0 = 0; s0 < chunk; s0 += 32) {
        const float4* s4 = reinterpret_cast<const float4*>(src + (size_t)(e0 + s0) * 64);
        float4* dv = reinterpret_cast<float4*>(v);
        dv[threadIdx.x] = s4[threadIdx.x];
        dv[threadIdx.x + 256] = s4[threadIdx.x + 256];
        __syncthreads();
#pragma unroll
        for (int e = 0; e < 32; ++e) {
            const float4 a = *reinterpret_cast<const float4*>(&v[e * 64 + r0]);
            const float4 b = *reinterpret_cast<const float4*>(&v[e * 64 + c0]);
            acc[0]  += a.x * b.x; acc[1]  += a.x * b.y; acc[2]  += a.x * b.z; acc[3]  += a.x * b.w;
            acc[4]  += a.y * b.x; acc[5]  += a.y * b.y; acc[6]  += a.y * b.z; acc[7]  += a.y * b.w;
            acc[8]  += a.z * b.x; acc[9]  += a.z * b.y; acc[10] += a.z * b.z; acc[11] += a.z * b.w;
            acc[12] += a.w * b.x; acc[13] += a.w * b.y; acc[14] += a.w * b.z; acc[15] += a.w * b.w;
        }
        __syncthreads();
    }
#pragma unroll
    for (int i = 0; i < 4; ++i)
#pragma unroll
        for (int j = 0; j < 4; ++j)
            atomicAdd(&K[(r0 + i) * 64 + (c0 + j)], (double)acc[i * 4 + j]);
}

__global__ void k_norm(const double* __restrict__ K, const double* __restrict__ sdiag,
                       float* __restrict__ out) {
    int idx = blockIdx.x * blockDim.x + threadIdx.x;   // 4096
    int r = idx >> 6, c = idx & 63;
    double kd = K[idx] + (r == c ? 4.0 * sdiag[r] : 0.0);
    double dr = K[(r << 6) | r] + 4.0 * sdiag[r];
    double dc = K[(c << 6) | c] + 4.0 * sdiag[c];
    out[idx] = (float)(kd / sqrt(dr * dc));
}

extern "C" void kernel_launch(void* const* d_in, const int* in_sizes, int n_in,
                              void* d_out, int out_size, void* d_ws, size_t ws_size,
                              hipStream_t stream) {
    const int* nbr = (const int*)d_in[0];       // [G, N, D] int32
    const float* w = (const float*)d_in[1];     // [G, N] float32
    float* out = (float*)d_out;                 // [G, G] float32

    char* ws = (char*)d_ws;
    size_t off = 0;
    auto alloc = [&](size_t bytes) -> void* {
        void* p = ws + off;
        off += (bytes + 255) & ~(size_t)255;
        return p;
    };
    double* Kacc  = (double*)alloc(64 * 64 * 8);                    // 32 KB
    int* counters = (int*)alloc(256);                               // novf[t]
    double* sdiag = (double*)alloc(64 * 8);                         // 512 B
    unsigned long long* table = (unsigned long long*)alloc(TBYTES); // 16 MB
    int* labelsA  = (int*)alloc((size_t)GN * 4);                    // 1 MB
    int* labelsB  = (int*)alloc((size_t)GN * 4);                    // 1 MB
    float* wT     = (float*)alloc((size_t)GN * 4);                  // 1 MB
    unsigned long long* ovf = (unsigned long long*)alloc((size_t)OVF_MAX * 8); // 2 MB

    // Kacc, counters, sdiag, table are contiguous -> one zero-memset
    hipMemsetAsync(Kacc, 0, 64 * 64 * 8 + 256 + 512 + TBYTES, stream);

    const int BLK = 256;

    // iteration 0: labels = arange shared across graphs -> K0 = W W^T
    k_init<<<GN / BLK, BLK, 0, stream>>>(labelsA, w, wT);
    k_fold<<<32, BLK, 0, stream>>>(wT, Kacc, NN / 32);
    k_diag<<<GG, BLK, 0, stream>>>(w, sdiag);

    int* cur = labelsA;
    int* nxt = labelsB;
    for (int t = 0; t < TT; ++t) {
        if (t > 0) hipMemsetAsync(table, 0, TBYTES, stream);
        k_hash<<<GN / 512, 512, 0, stream>>>(cur, nbr, table, w, Kacc, ovf,
                                             &counters[t], nxt,
                                             NN + t * (1 << PBITS));
        k_resolve<<<OVF_MAX / BLK, BLK, 0, stream>>>(ovf, &counters[t], w, Kacc);
        int* tmp = cur; cur = nxt; nxt = tmp;
    }

    k_norm<<<(GG * GG) / BLK, BLK, 0, stream>>>(Kacc, sdiag, out);
}